// Round 4
// baseline (288.592 us; speedup 1.0000x reference)
//
#include <hip/hip_runtime.h>
#include <stdint.h>

// Problem constants (from reference)
#define N_NODES 50000
#define DEG     32
#define IN_DIM  256
#define K1      512   // 2*IN_DIM
#define HID     256
#define OUT_DIM 128

#define NCHUNK  8                      // feature-dim chunks
#define CDIM    32                     // dims per chunk
#define SLICE   ((size_t)N_NODES * CDIM)  // elems per chunk slice (1.6M, 3.2 MB bf16)

#define MT   32    // nodes per block tile (GEMM kernel)
#define CSTR 520   // combined LDS row stride in bf16 elems (1040 B = 65*16)
#define HSTR 264   // h LDS row stride in bf16 elems (528 B = 33*16)
#define GT   64    // nodes per gather block

typedef __bf16 bf16x8 __attribute__((ext_vector_type(8)));
typedef float  f32x4  __attribute__((ext_vector_type(4)));

__device__ __forceinline__ unsigned short f2bf(float f) {
    union { float f; unsigned u; } v; v.f = f;
    unsigned r = v.u + 0x7fffu + ((v.u >> 16) & 1u);  // RNE (inputs finite)
    return (unsigned short)(r >> 16);
}
__device__ __forceinline__ float bf2f(unsigned short h) {
    union { unsigned u; float f; } v; v.u = ((unsigned)h) << 16;
    return v.f;
}
__device__ __forceinline__ int clampN(int v) {
    return v < 0 ? 0 : (v >= N_NODES ? N_NODES - 1 : v);
}

// ---------------- feat fp32 -> bf16 TILED [chunk][node][32] ----------------
__global__ __launch_bounds__(256)
void cvt_feat_tiled(const float* __restrict__ feat, unsigned short* __restrict__ featT) {
    const int t    = threadIdx.x;
    const int node = blockIdx.x * 8 + (t >> 5);  // 8 nodes/block
    const int seg  = t & 31;                     // 8-dim segment: dims seg*8 .. seg*8+7
    if (node < N_NODES) {
        const float4* src = (const float4*)(feat + (size_t)node * IN_DIM + seg * 8);
        float4 f0 = src[0], f1 = src[1];
        ushort4 o0, o1;
        o0.x = f2bf(f0.x); o0.y = f2bf(f0.y); o0.z = f2bf(f0.z); o0.w = f2bf(f0.w);
        o1.x = f2bf(f1.x); o1.y = f2bf(f1.y); o1.z = f2bf(f1.z); o1.w = f2bf(f1.w);
        const int c   = seg >> 2;        // chunk
        const int off = (seg & 3) * 8;   // offset within chunk
        unsigned short* dst = featT + (size_t)c * SLICE + (size_t)node * CDIM + off;
        *(ushort4*)dst       = o0;
        *(ushort4*)(dst + 4) = o1;
    }
}

// ---------------- small prep: W1/W2 cvt + nbr clamp->u16 (grid-stride) ----------------
__global__ __launch_bounds__(256)
void prep_small(const float* __restrict__ W1, const float* __restrict__ W2,
                const int* __restrict__ nbr,
                unsigned short* __restrict__ W1b, unsigned short* __restrict__ W2b,
                unsigned short* __restrict__ nbr16) {
    const int stride = gridDim.x * blockDim.x * 4;
    const int tid4 = (blockIdx.x * blockDim.x + threadIdx.x) * 4;
    for (int i = tid4; i < HID * K1; i += stride) {          // 131072, /4 exact
        float4 f = *(const float4*)(W1 + i);
        ushort4 o; o.x = f2bf(f.x); o.y = f2bf(f.y); o.z = f2bf(f.z); o.w = f2bf(f.w);
        *(ushort4*)(W1b + i) = o;
    }
    for (int i = tid4; i < OUT_DIM * HID; i += stride) {     // 32768, /4 exact
        float4 f = *(const float4*)(W2 + i);
        ushort4 o; o.x = f2bf(f.x); o.y = f2bf(f.y); o.z = f2bf(f.z); o.w = f2bf(f.w);
        *(ushort4*)(W2b + i) = o;
    }
    for (int i = tid4; i < N_NODES * DEG; i += stride) {     // 1.6M, /4 exact
        int4 v = *(const int4*)(nbr + i);
        ushort4 o;
        o.x = (unsigned short)clampN(v.x); o.y = (unsigned short)clampN(v.y);
        o.z = (unsigned short)clampN(v.z); o.w = (unsigned short)clampN(v.w);
        *(ushort4*)(nbr16 + i) = o;
    }
}

// ---------------- gather + mean, L2-resident slice version ----------------
// grid = (ceil(N/GT), NCHUNK), chunk in blockIdx.y (slow dim) so the active
// window of blocks all read the SAME 3.2 MB slice -> per-XCD L2 resident.
__global__ __launch_bounds__(256)
void gather_mean_tiled(const unsigned short* __restrict__ featT,
                       const unsigned short* __restrict__ nbr16,
                       unsigned short*       __restrict__ meanb)  // [N,256] bf16
{
    __shared__ unsigned short sIdx[GT * DEG];  // 4 KB
    const int tid  = threadIdx.x;
    const int c    = blockIdx.y;
    const int base = blockIdx.x * GT;

    // stage 2048 u16 indices (16 B/thread), guarded at the tail
    {
        const unsigned short* g = nbr16 + (size_t)base * DEG;
        const int rem = (N_NODES - base) * DEG;   // >0
        int li = tid * 8;
        if (li + 7 < rem) {
            *(ushort4*)(sIdx + li)     = *(const ushort4*)(g + li);
            *(ushort4*)(sIdx + li + 4) = *(const ushort4*)(g + li + 4);
        } else {
            for (int j = 0; j < 8; ++j) sIdx[li + j] = (li + j < rem) ? g[li + j] : 0;
        }
    }
    __syncthreads();

    const unsigned short* slice = featT + (size_t)c * SLICE;
    const int grp = tid >> 4;     // node slot (0..15)
    const int ln  = tid & 15;     // covers dims 2*ln, 2*ln+1 of the chunk

    #pragma unroll
    for (int p = 0; p < 4; ++p) {
        const int local = p * 16 + grp;        // 0..63
        const int node  = base + local;
        const unsigned short* idxr = sIdx + local * DEG;
        float s0 = 0.f, s1 = 0.f;
        #pragma unroll 16
        for (int j = 0; j < DEG; ++j) {
            int nb = idxr[j];   // LDS broadcast within 16-lane group
            ushort2 v = *(const ushort2*)(slice + (size_t)nb * CDIM + ln * 2);
            s0 += bf2f(v.x); s1 += bf2f(v.y);
        }
        if (node < N_NODES) {
            ushort2 o;
            o.x = f2bf(s0 * (1.0f / 32.0f));
            o.y = f2bf(s1 * (1.0f / 32.0f));
            *(ushort2*)(meanb + (size_t)node * IN_DIM + c * CDIM + ln * 2) = o;
        }
    }
}

// ---------------- fused GEMM1 + GEMM2 (bf16 MFMA) ----------------
// MFMA fragment layouts (measured, learn_hip m89/m91/m120):
//   A operand: lane holds A[m = lane&15][k = (lane>>4)*8 + j], j=0..7
//   B operand (W row-major [n][k]): lane holds W[n = lane&15][k = (lane>>4)*8 + j]
//   C/D: col(n) = lane&15, row(m) = (lane>>4)*4 + reg
__global__ __launch_bounds__(256)
void sage_gemm(const unsigned short* __restrict__ featT,  // [8][N][32] bf16
               const unsigned short* __restrict__ meanb,  // [N, 256] bf16
               const unsigned short* __restrict__ W1b,    // [256, 512] bf16
               const float*          __restrict__ b1,     // [256]
               const unsigned short* __restrict__ W2b,    // [128, 256] bf16
               const float*          __restrict__ b2,     // [128]
               float*                __restrict__ out)    // [N, 128]
{
    // sH aliases sC (sC is dead once every wave finishes its phase-2 k-loop):
    // LDS 33280 B -> 4 blocks/CU (was 50 KB -> 3).
    __shared__ __align__(16) unsigned short sBuf[MT * CSTR]; // 33280 B
    unsigned short* sC = sBuf;
    unsigned short* sH = sBuf;

    const int tid  = threadIdx.x;
    const int lane = tid & 63;
    const int wave = tid >> 6;
    const int base = blockIdx.x * MT;

    // ---- Phase 1: stage combined = [self | mean] rows into sC (16 B/lane) ----
    for (int i = wave * 8; i < wave * 8 + 8; ++i) {
        const int node = base + i;
        if (node < N_NODES) {
            const unsigned short* src;
            if (lane < 32) {
                // self row, dims lane*8..lane*8+7 from tiled layout
                const int c   = lane >> 2;
                const int off = (lane & 3) * 8;
                src = featT + (size_t)c * SLICE + (size_t)node * CDIM + off;
            } else {
                src = meanb + (size_t)node * IN_DIM + (lane - 32) * 8;
            }
            *(bf16x8*)(&sC[i * CSTR + lane * 8]) = *(const bf16x8*)src;
        } else {
            bf16x8 z = (bf16x8){0, 0, 0, 0, 0, 0, 0, 0};
            *(bf16x8*)(&sC[i * CSTR + lane * 8]) = z;
        }
    }
    __syncthreads();

    const int r = lane & 15;      // fragment row / output col
    const int q = lane >> 4;      // quad

    // ---- Phase 2: h = relu(combined @ W1^T + b1), wave computes cols [wave*64, wave*64+64) ----
    {
        f32x4 acc[2][4];
        #pragma unroll
        for (int mt = 0; mt < 2; ++mt)
            #pragma unroll
            for (int nt = 0; nt < 4; ++nt)
                acc[mt][nt] = (f32x4){0.f, 0.f, 0.f, 0.f};

        for (int k0 = 0; k0 < K1; k0 += 32) {
            bf16x8 a0 = *(const bf16x8*)(&sC[r * CSTR + k0 + q * 8]);
            bf16x8 a1 = *(const bf16x8*)(&sC[(16 + r) * CSTR + k0 + q * 8]);
            #pragma unroll
            for (int nt = 0; nt < 4; ++nt) {
                int n = wave * 64 + nt * 16 + r;
                bf16x8 b = *(const bf16x8*)(W1b + (size_t)n * K1 + k0 + q * 8);
                acc[0][nt] = __builtin_amdgcn_mfma_f32_16x16x32_bf16(a0, b, acc[0][nt], 0, 0, 0);
                acc[1][nt] = __builtin_amdgcn_mfma_f32_16x16x32_bf16(a1, b, acc[1][nt], 0, 0, 0);
            }
        }
        __syncthreads();   // all waves done reading sC before sH (aliased) is written
        #pragma unroll
        for (int nt = 0; nt < 4; ++nt) {
            int n = wave * 64 + nt * 16 + r;
            float bias = b1[n];
            #pragma unroll
            for (int mt = 0; mt < 2; ++mt)
                #pragma unroll
                for (int g = 0; g < 4; ++g) {
                    int m = mt * 16 + q * 4 + g;
                    float v = acc[mt][nt][g] + bias;
                    sH[m * HSTR + n] = f2bf(v > 0.f ? v : 0.f);
                }
        }
    }
    __syncthreads();

    // ---- Phase 3: out = relu(h @ W2^T + b2), wave computes cols [wave*32, wave*32+32) ----
    {
        f32x4 acc[2][2];
        #pragma unroll
        for (int mt = 0; mt < 2; ++mt)
            #pragma unroll
            for (int nt = 0; nt < 2; ++nt)
                acc[mt][nt] = (f32x4){0.f, 0.f, 0.f, 0.f};

        for (int k0 = 0; k0 < HID; k0 += 32) {
            bf16x8 a0 = *(const bf16x8*)(&sH[r * HSTR + k0 + q * 8]);
            bf16x8 a1 = *(const bf16x8*)(&sH[(16 + r) * HSTR + k0 + q * 8]);
            #pragma unroll
            for (int nt = 0; nt < 2; ++nt) {
                int o = wave * 32 + nt * 16 + r;
                bf16x8 b = *(const bf16x8*)(W2b + (size_t)o * HID + k0 + q * 8);
                acc[0][nt] = __builtin_amdgcn_mfma_f32_16x16x32_bf16(a0, b, acc[0][nt], 0, 0, 0);
                acc[1][nt] = __builtin_amdgcn_mfma_f32_16x16x32_bf16(a1, b, acc[1][nt], 0, 0, 0);
            }
        }
        #pragma unroll
        for (int nt = 0; nt < 2; ++nt) {
            int o = wave * 32 + nt * 16 + r;
            float bias = b2[o];
            #pragma unroll
            for (int mt = 0; mt < 2; ++mt)
                #pragma unroll
                for (int g = 0; g < 4; ++g) {
                    int m = mt * 16 + q * 4 + g;
                    int node = base + m;
                    if (node < N_NODES) {
                        float v = acc[mt][nt][g] + bias;
                        out[(size_t)node * OUT_DIM + o] = v > 0.f ? v : 0.f;
                    }
                }
        }
    }
}

// ---------------- naive fp32 fallback (only if ws too small) ----------------
__global__ __launch_bounds__(256)
void sage_naive(const float* __restrict__ feat, const int* __restrict__ nbr,
                const float* __restrict__ W1, const float* __restrict__ b1,
                const float* __restrict__ W2, const float* __restrict__ b2,
                float* __restrict__ out) {
    __shared__ float comb[K1];
    __shared__ float h[HID];
    const int node = blockIdx.x;
    const int t = threadIdx.x;  // 256
    comb[t] = feat[(size_t)node * IN_DIM + t];
    float acc = 0.f;
    for (int d = 0; d < DEG; ++d) {
        int nb = clampN(nbr[node * DEG + d]);
        acc += feat[(size_t)nb * IN_DIM + t];
    }
    comb[IN_DIM + t] = acc * (1.0f / 32.0f);
    __syncthreads();
    float s = b1[t];
    for (int k = 0; k < K1; ++k) s += comb[k] * W1[(size_t)t * K1 + k];
    h[t] = s > 0.f ? s : 0.f;
    __syncthreads();
    if (t < OUT_DIM) {
        float s2 = b2[t];
        for (int k = 0; k < HID; ++k) s2 += h[k] * W2[(size_t)t * HID + k];
        out[(size_t)node * OUT_DIM + t] = s2 > 0.f ? s2 : 0.f;
    }
}

extern "C" void kernel_launch(void* const* d_in, const int* in_sizes, int n_in,
                              void* d_out, int out_size, void* d_ws, size_t ws_size,
                              hipStream_t stream) {
    const float* feat = (const float*)d_in[0];
    const int*   nbr  = (const int*)d_in[1];
    const float* W1   = (const float*)d_in[2];
    const float* b1   = (const float*)d_in[3];
    const float* W2   = (const float*)d_in[4];
    const float* b2   = (const float*)d_in[5];
    float* out = (float*)d_out;

    const size_t feat_elems = (size_t)N_NODES * IN_DIM;   // 12.8M
    const size_t w1_elems   = (size_t)HID * K1;           // 131072
    const size_t w2_elems   = (size_t)OUT_DIM * HID;      // 32768
    const size_t mean_elems = (size_t)N_NODES * IN_DIM;   // 12.8M
    const size_t idx_elems  = (size_t)N_NODES * DEG;      // 1.6M
    const size_t need = (feat_elems + w1_elems + w2_elems + mean_elems + idx_elems)
                        * sizeof(unsigned short);         // ~54.8 MB

    if (ws_size >= need) {
        unsigned short* featT = (unsigned short*)d_ws;
        unsigned short* W1b   = featT + feat_elems;
        unsigned short* W2b   = W1b + w1_elems;
        unsigned short* meanb = W2b + w2_elems;
        unsigned short* nbr16 = meanb + mean_elems;

        cvt_feat_tiled<<<(N_NODES + 7) / 8, 256, 0, stream>>>(feat, featT);
        prep_small<<<256, 256, 0, stream>>>(W1, W2, nbr, W1b, W2b, nbr16);
        gather_mean_tiled<<<dim3((N_NODES + GT - 1) / GT, NCHUNK), 256, 0, stream>>>(featT, nbr16, meanb);
        sage_gemm<<<(N_NODES + MT - 1) / MT, 256, 0, stream>>>(featT, meanb, W1b, b1, W2b, b2, out);
    } else {
        sage_naive<<<N_NODES, 256, 0, stream>>>(feat, nbr, W1, b1, W2, b2, out);
    }
}

// Round 5
// 194.857 us; speedup vs baseline: 1.4810x; 1.4810x over previous
//
#include <hip/hip_runtime.h>
#include <stdint.h>

// Problem constants (from reference)
#define N_NODES 50000
#define DEG     32
#define IN_DIM  256
#define K1      512   // 2*IN_DIM
#define HID     256
#define OUT_DIM 128

// fp8 gather tiling
#define NCHUNK  4
#define CDIM    64                          // dims per chunk (64 B fp8 per node-chunk)
#define SLICE8  ((size_t)N_NODES * CDIM)    // bytes per chunk slice (3.2 MB)
#define GT      16                          // nodes per gather block (50000 % 16 == 0)

// GEMM tiling
#define MT   64    // nodes per block tile
#define CSTR 520   // combined LDS row stride, bf16 elems (1040 B; 2-way LDS alias only)
#define HSTR 264   // h LDS row stride, bf16 elems (528 B)

typedef __bf16 bf16x8 __attribute__((ext_vector_type(8)));
typedef float  f32x4  __attribute__((ext_vector_type(4)));
typedef float  f32x2  __attribute__((ext_vector_type(2)));

__device__ __forceinline__ unsigned short f2bf(float f) {
    union { float f; unsigned u; } v; v.f = f;
    unsigned r = v.u + 0x7fffu + ((v.u >> 16) & 1u);  // RNE (inputs finite)
    return (unsigned short)(r >> 16);
}
__device__ __forceinline__ int clampN(int v) {
    return v < 0 ? 0 : (v >= N_NODES ? N_NODES - 1 : v);
}

// ---------------- feat fp32 -> bf16 linear + fp8 tiled [4][N][64] ----------------
__global__ __launch_bounds__(256)
void cvt_feat(const float* __restrict__ feat,
              unsigned short* __restrict__ featb,   // [N,256] bf16
              unsigned char*  __restrict__ featF8)  // [4][N][64] fp8 e4m3 (HW fmt)
{
    const int t    = threadIdx.x;
    const int node = blockIdx.x * 8 + (t >> 5);  // 8 nodes/block
    const int seg  = t & 31;                     // dims seg*8 .. seg*8+7
    if (node < N_NODES) {
        const float4* src = (const float4*)(feat + (size_t)node * IN_DIM + seg * 8);
        float4 f0 = src[0], f1 = src[1];
        // bf16 linear
        ushort4 o0, o1;
        o0.x = f2bf(f0.x); o0.y = f2bf(f0.y); o0.z = f2bf(f0.z); o0.w = f2bf(f0.w);
        o1.x = f2bf(f1.x); o1.y = f2bf(f1.y); o1.z = f2bf(f1.z); o1.w = f2bf(f1.w);
        unsigned short* db = featb + (size_t)node * IN_DIM + seg * 8;
        *(ushort4*)db       = o0;
        *(ushort4*)(db + 4) = o1;
        // fp8 tiled (HW pack: bytes in order f.x,f.y,f.z,f.w)
        int u0 = 0, u1 = 0;
        u0 = __builtin_amdgcn_cvt_pk_fp8_f32(f0.x, f0.y, u0, false);
        u0 = __builtin_amdgcn_cvt_pk_fp8_f32(f0.z, f0.w, u0, true);
        u1 = __builtin_amdgcn_cvt_pk_fp8_f32(f1.x, f1.y, u1, false);
        u1 = __builtin_amdgcn_cvt_pk_fp8_f32(f1.z, f1.w, u1, true);
        const int c   = seg >> 3;        // chunk (8 segs of 8 dims = 64 dims)
        const int off = (seg & 7) * 8;
        unsigned char* d8 = featF8 + (size_t)c * SLICE8 + (size_t)node * CDIM + off;
        ((int*)d8)[0] = u0;
        ((int*)d8)[1] = u1;
    }
}

// ---------------- small prep: W1/W2 cvt + nbr clamp->u16 (grid-stride) ----------------
__global__ __launch_bounds__(256)
void prep_small(const float* __restrict__ W1, const float* __restrict__ W2,
                const int* __restrict__ nbr,
                unsigned short* __restrict__ W1b, unsigned short* __restrict__ W2b,
                unsigned short* __restrict__ nbr16) {
    const int stride = gridDim.x * blockDim.x * 4;
    const int tid4 = (blockIdx.x * blockDim.x + threadIdx.x) * 4;
    for (int i = tid4; i < HID * K1; i += stride) {
        float4 f = *(const float4*)(W1 + i);
        ushort4 o; o.x = f2bf(f.x); o.y = f2bf(f.y); o.z = f2bf(f.z); o.w = f2bf(f.w);
        *(ushort4*)(W1b + i) = o;
    }
    for (int i = tid4; i < OUT_DIM * HID; i += stride) {
        float4 f = *(const float4*)(W2 + i);
        ushort4 o; o.x = f2bf(f.x); o.y = f2bf(f.y); o.z = f2bf(f.z); o.w = f2bf(f.w);
        *(ushort4*)(W2b + i) = o;
    }
    for (int i = tid4; i < N_NODES * DEG; i += stride) {
        int4 v = *(const int4*)(nbr + i);
        ushort4 o;
        o.x = (unsigned short)clampN(v.x); o.y = (unsigned short)clampN(v.y);
        o.z = (unsigned short)clampN(v.z); o.w = (unsigned short)clampN(v.w);
        *(ushort4*)(nbr16 + i) = o;
    }
}

// ---------------- gather + mean: fp8 slices, truly L2-resident ----------------
// grid = (3125, 4): 3125 blocks/chunk >> ~2048 co-resident -> one 3.2 MB slice
// active per XCD-L2 at a time. 16-lane group per node, uint load = 4 fp8 dims.
__global__ __launch_bounds__(256)
void gather_mean_fp8(const unsigned char*  __restrict__ featF8,
                     const unsigned short* __restrict__ nbr16,
                     unsigned short*       __restrict__ meanb)  // [N,256] bf16
{
    __shared__ unsigned short sIdx[GT * DEG];  // 1 KB
    const int tid  = threadIdx.x;
    const int c    = blockIdx.y;
    const int base = blockIdx.x * GT;          // N % GT == 0: no tail

    if (tid < 128) {
        *(ushort4*)(sIdx + tid * 4) =
            *(const ushort4*)(nbr16 + (size_t)base * DEG + tid * 4);
    }
    __syncthreads();

    const unsigned char* slice = featF8 + (size_t)c * SLICE8;
    const int grp = tid >> 4;     // node slot 0..15
    const int ln  = tid & 15;     // dims 4*ln .. 4*ln+3 of the chunk
    const unsigned short* idxr = sIdx + grp * DEG;

    float s0 = 0.f, s1 = 0.f, s2 = 0.f, s3 = 0.f;
    #pragma unroll 8
    for (int j = 0; j < DEG; ++j) {
        int nb = idxr[j];
        unsigned v = *(const unsigned*)(slice + (size_t)nb * CDIM + ln * 4);
        f32x2 lo = __builtin_amdgcn_cvt_pk_f32_fp8(v, false);
        f32x2 hi = __builtin_amdgcn_cvt_pk_f32_fp8(v, true);
        s0 += lo[0]; s1 += lo[1]; s2 += hi[0]; s3 += hi[1];
    }
    const float sc = 1.0f / 32.0f;
    ushort4 o;
    o.x = f2bf(s0 * sc); o.y = f2bf(s1 * sc);
    o.z = f2bf(s2 * sc); o.w = f2bf(s3 * sc);
    const int node = base + grp;
    *(ushort4*)(meanb + (size_t)node * IN_DIM + c * CDIM + ln * 4) = o;
}

// ---------------- fused GEMM1 + GEMM2 (bf16 MFMA), MT=64, 512 threads ----------------
// MFMA fragment layouts (measured, learn_hip m89/m91/m120):
//   A operand: lane holds A[m = lane&15][k = (lane>>4)*8 + j], j=0..7
//   B operand (W row-major [n][k]): lane holds W[n = lane&15][k = (lane>>4)*8 + j]
//   C/D: col(n) = lane&15, row(m) = (lane>>4)*4 + reg
__global__ __launch_bounds__(512, 4)
void sage_gemm(const unsigned short* __restrict__ featb,  // [N,256] bf16
               const unsigned short* __restrict__ meanb,  // [N,256] bf16
               const unsigned short* __restrict__ W1b,    // [256,512] bf16
               const float*          __restrict__ b1,
               const unsigned short* __restrict__ W2b,    // [128,256] bf16
               const float*          __restrict__ b2,
               float*                __restrict__ out)    // [N,128]
{
    __shared__ __align__(16) unsigned short sBuf[MT * CSTR]; // 66560 B -> 2 blocks/CU
    unsigned short* sC = sBuf;
    unsigned short* sH = sBuf;   // aliased: sC dead after phase-2 k-loop barrier

    const int tid  = threadIdx.x;
    const int lane = tid & 63;
    const int wave = tid >> 6;   // 0..7
    const int base = blockIdx.x * MT;

    // ---- Phase 1: stage combined = [self | mean] rows (16 B/lane) ----
    for (int i = wave * 8; i < wave * 8 + 8; ++i) {
        const int node = base + i;
        if (node < N_NODES) {
            const unsigned short* src = (lane < 32)
                ? featb + (size_t)node * IN_DIM + lane * 8
                : meanb + (size_t)node * IN_DIM + (lane - 32) * 8;
            *(bf16x8*)(&sC[i * CSTR + lane * 8]) = *(const bf16x8*)src;
        } else {
            bf16x8 z = (bf16x8){0, 0, 0, 0, 0, 0, 0, 0};
            *(bf16x8*)(&sC[i * CSTR + lane * 8]) = z;
        }
    }
    __syncthreads();

    const int r = lane & 15;
    const int q = lane >> 4;

    // ---- Phase 2: h = relu(C @ W1^T + b1); wave covers h-cols [wave*32, wave*32+32) ----
    {
        f32x4 acc[4][2];
        #pragma unroll
        for (int mt = 0; mt < 4; ++mt)
            #pragma unroll
            for (int nt = 0; nt < 2; ++nt)
                acc[mt][nt] = (f32x4){0.f, 0.f, 0.f, 0.f};

        for (int k0 = 0; k0 < K1; k0 += 32) {
            bf16x8 a[4];
            #pragma unroll
            for (int mt = 0; mt < 4; ++mt)
                a[mt] = *(const bf16x8*)(&sC[(mt * 16 + r) * CSTR + k0 + q * 8]);
            #pragma unroll
            for (int nt = 0; nt < 2; ++nt) {
                int n = wave * 32 + nt * 16 + r;
                bf16x8 b = *(const bf16x8*)(W1b + (size_t)n * K1 + k0 + q * 8);
                #pragma unroll
                for (int mt = 0; mt < 4; ++mt)
                    acc[mt][nt] = __builtin_amdgcn_mfma_f32_16x16x32_bf16(a[mt], b, acc[mt][nt], 0, 0, 0);
            }
        }
        __syncthreads();   // everyone done reading sC before sH (aliased) is written
        #pragma unroll
        for (int nt = 0; nt < 2; ++nt) {
            int n = wave * 32 + nt * 16 + r;
            float bias = b1[n];
            #pragma unroll
            for (int mt = 0; mt < 4; ++mt)
                #pragma unroll
                for (int g = 0; g < 4; ++g) {
                    int m = mt * 16 + q * 4 + g;
                    float v = acc[mt][nt][g] + bias;
                    sH[m * HSTR + n] = f2bf(v > 0.f ? v : 0.f);
                }
        }
    }
    __syncthreads();

    // ---- Phase 3: out = relu(h @ W2^T + b2); wave covers out-cols [wave*16, wave*16+16) ----
    {
        f32x4 acc[4];
        #pragma unroll
        for (int mt = 0; mt < 4; ++mt) acc[mt] = (f32x4){0.f, 0.f, 0.f, 0.f};

        const int o = wave * 16 + r;
        for (int k0 = 0; k0 < HID; k0 += 32) {
            bf16x8 b = *(const bf16x8*)(W2b + (size_t)o * HID + k0 + q * 8);
            #pragma unroll
            for (int mt = 0; mt < 4; ++mt) {
                bf16x8 a = *(const bf16x8*)(&sH[(mt * 16 + r) * HSTR + k0 + q * 8]);
                acc[mt] = __builtin_amdgcn_mfma_f32_16x16x32_bf16(a, b, acc[mt], 0, 0, 0);
            }
        }
        float bias = b2[o];
        #pragma unroll
        for (int mt = 0; mt < 4; ++mt)
            #pragma unroll
            for (int g = 0; g < 4; ++g) {
                int m = mt * 16 + q * 4 + g;
                int node = base + m;
                if (node < N_NODES) {
                    float v = acc[mt][g] + bias;
                    out[(size_t)node * OUT_DIM + o] = v > 0.f ? v : 0.f;
                }
            }
    }
}

// ---------------- naive fp32 fallback (only if ws too small) ----------------
__global__ __launch_bounds__(256)
void sage_naive(const float* __restrict__ feat, const int* __restrict__ nbr,
                const float* __restrict__ W1, const float* __restrict__ b1,
                const float* __restrict__ W2, const float* __restrict__ b2,
                float* __restrict__ out) {
    __shared__ float comb[K1];
    __shared__ float h[HID];
    const int node = blockIdx.x;
    const int t = threadIdx.x;  // 256
    comb[t] = feat[(size_t)node * IN_DIM + t];
    float acc = 0.f;
    for (int d = 0; d < DEG; ++d) {
        int nb = clampN(nbr[node * DEG + d]);
        acc += feat[(size_t)nb * IN_DIM + t];
    }
    comb[IN_DIM + t] = acc * (1.0f / 32.0f);
    __syncthreads();
    float s = b1[t];
    for (int k = 0; k < K1; ++k) s += comb[k] * W1[(size_t)t * K1 + k];
    h[t] = s > 0.f ? s : 0.f;
    __syncthreads();
    if (t < OUT_DIM) {
        float s2 = b2[t];
        for (int k = 0; k < HID; ++k) s2 += h[k] * W2[(size_t)t * HID + k];
        out[(size_t)node * OUT_DIM + t] = s2 > 0.f ? s2 : 0.f;
    }
}

extern "C" void kernel_launch(void* const* d_in, const int* in_sizes, int n_in,
                              void* d_out, int out_size, void* d_ws, size_t ws_size,
                              hipStream_t stream) {
    const float* feat = (const float*)d_in[0];
    const int*   nbr  = (const int*)d_in[1];
    const float* W1   = (const float*)d_in[2];
    const float* b1   = (const float*)d_in[3];
    const float* W2   = (const float*)d_in[4];
    const float* b2   = (const float*)d_in[5];
    float* out = (float*)d_out;

    const size_t feat_elems = (size_t)N_NODES * IN_DIM;   // 12.8M
    const size_t w1_elems   = (size_t)HID * K1;
    const size_t w2_elems   = (size_t)OUT_DIM * HID;
    const size_t mean_elems = (size_t)N_NODES * IN_DIM;
    const size_t idx_elems  = (size_t)N_NODES * DEG;
    const size_t u16_elems  = feat_elems + w1_elems + w2_elems + mean_elems + idx_elems;
    const size_t need = u16_elems * sizeof(unsigned short)
                      + (size_t)NCHUNK * SLICE8;          // + 12.8 MB fp8 -> ~67.6 MB

    if (ws_size >= need) {
        unsigned short* featb  = (unsigned short*)d_ws;
        unsigned short* W1b    = featb + feat_elems;
        unsigned short* W2b    = W1b + w1_elems;
        unsigned short* meanb  = W2b + w2_elems;
        unsigned short* nbr16  = meanb + mean_elems;
        unsigned char*  featF8 = (unsigned char*)(nbr16 + idx_elems);

        cvt_feat<<<(N_NODES + 7) / 8, 256, 0, stream>>>(feat, featb, featF8);
        prep_small<<<256, 256, 0, stream>>>(W1, W2, nbr, W1b, W2b, nbr16);
        gather_mean_fp8<<<dim3(N_NODES / GT, NCHUNK), 256, 0, stream>>>(featF8, nbr16, meanb);
        sage_gemm<<<(N_NODES + MT - 1) / MT, 512, 0, stream>>>(featb, meanb, W1b, b1, W2b, b2, out);
    } else {
        sage_naive<<<N_NODES, 256, 0, stream>>>(feat, nbr, W1, b1, W2, b2, out);
    }
}

// Round 6
// 187.095 us; speedup vs baseline: 1.5425x; 1.0415x over previous
//
#include <hip/hip_runtime.h>
#include <stdint.h>

// Problem constants (from reference)
#define N_NODES 50000
#define DEG     32
#define IN_DIM  256
#define K1      512   // 2*IN_DIM
#define HID     256
#define OUT_DIM 128

// fp8 gather tiling
#define NCHUNK  4
#define CDIM    64                          // dims per chunk (64 B fp8 per node-chunk)
#define SLICE8  ((size_t)N_NODES * CDIM)    // bytes per chunk slice (3.2 MB)
#define GT      16                          // nodes per gather block

// GEMM tiling
#define MT     64     // nodes per tile
#define NTILES 782    // ceil(N/MT)
#define GBLK   256    // persistent blocks (1/CU)
#define CSTR   520    // combined LDS row stride, bf16 elems (1040 B)
#define HSTR   264    // h LDS row stride, bf16 elems (528 B)

typedef __bf16 bf16x8 __attribute__((ext_vector_type(8)));
typedef float  f32x4  __attribute__((ext_vector_type(4)));
typedef float  f32x2  __attribute__((ext_vector_type(2)));

__device__ __forceinline__ unsigned short f2bf(float f) {
    union { float f; unsigned u; } v; v.f = f;
    unsigned r = v.u + 0x7fffu + ((v.u >> 16) & 1u);  // RNE (inputs finite)
    return (unsigned short)(r >> 16);
}
__device__ __forceinline__ int clampN(int v) {
    return v < 0 ? 0 : (v >= N_NODES ? N_NODES - 1 : v);
}

// ---------------- merged prep: feat->bf16 + fp8 tiled; W1/W2->bf16; nbr->u16 ----------------
#define FEAT_BLKS ((N_NODES + 7) / 8)   // 6250
__global__ __launch_bounds__(256)
void prep_all(const float* __restrict__ feat,
              const float* __restrict__ W1, const float* __restrict__ W2,
              const int*   __restrict__ nbr,
              unsigned short* __restrict__ featb,   // [N,256] bf16
              unsigned char*  __restrict__ featF8,  // [4][N][64] fp8 e4m3
              unsigned short* __restrict__ W1b, unsigned short* __restrict__ W2b,
              unsigned short* __restrict__ nbr16)
{
    const int t = threadIdx.x;
    if (blockIdx.x < FEAT_BLKS) {
        const int node = blockIdx.x * 8 + (t >> 5);  // 8 nodes/block
        const int seg  = t & 31;                     // dims seg*8 .. seg*8+7
        if (node < N_NODES) {
            const float4* src = (const float4*)(feat + (size_t)node * IN_DIM + seg * 8);
            float4 f0 = src[0], f1 = src[1];
            ushort4 o0, o1;
            o0.x = f2bf(f0.x); o0.y = f2bf(f0.y); o0.z = f2bf(f0.z); o0.w = f2bf(f0.w);
            o1.x = f2bf(f1.x); o1.y = f2bf(f1.y); o1.z = f2bf(f1.z); o1.w = f2bf(f1.w);
            unsigned short* db = featb + (size_t)node * IN_DIM + seg * 8;
            *(ushort4*)db       = o0;
            *(ushort4*)(db + 4) = o1;
            int u0 = 0, u1 = 0;
            u0 = __builtin_amdgcn_cvt_pk_fp8_f32(f0.x, f0.y, u0, false);
            u0 = __builtin_amdgcn_cvt_pk_fp8_f32(f0.z, f0.w, u0, true);
            u1 = __builtin_amdgcn_cvt_pk_fp8_f32(f1.x, f1.y, u1, false);
            u1 = __builtin_amdgcn_cvt_pk_fp8_f32(f1.z, f1.w, u1, true);
            const int c   = seg >> 3;
            const int off = (seg & 7) * 8;
            unsigned char* d8 = featF8 + (size_t)c * SLICE8 + (size_t)node * CDIM + off;
            ((int*)d8)[0] = u0;
            ((int*)d8)[1] = u1;
        }
    } else {
        const int bid = blockIdx.x - FEAT_BLKS;           // 0..255
        const int stride = 256 * 256 * 4;
        const int tid4 = (bid * 256 + t) * 4;
        for (int i = tid4; i < HID * K1; i += stride) {
            float4 f = *(const float4*)(W1 + i);
            ushort4 o; o.x = f2bf(f.x); o.y = f2bf(f.y); o.z = f2bf(f.z); o.w = f2bf(f.w);
            *(ushort4*)(W1b + i) = o;
        }
        for (int i = tid4; i < OUT_DIM * HID; i += stride) {
            float4 f = *(const float4*)(W2 + i);
            ushort4 o; o.x = f2bf(f.x); o.y = f2bf(f.y); o.z = f2bf(f.z); o.w = f2bf(f.w);
            *(ushort4*)(W2b + i) = o;
        }
        for (int i = tid4; i < N_NODES * DEG; i += stride) {
            int4 v = *(const int4*)(nbr + i);
            ushort4 o;
            o.x = (unsigned short)clampN(v.x); o.y = (unsigned short)clampN(v.y);
            o.z = (unsigned short)clampN(v.z); o.w = (unsigned short)clampN(v.w);
            *(ushort4*)(nbr16 + i) = o;
        }
    }
}

// ---------------- gather + mean: fp8 slices, L2-resident (unchanged) ----------------
__global__ __launch_bounds__(256)
void gather_mean_fp8(const unsigned char*  __restrict__ featF8,
                     const unsigned short* __restrict__ nbr16,
                     unsigned short*       __restrict__ meanb)  // [N,256] bf16
{
    __shared__ unsigned short sIdx[GT * DEG];  // 1 KB
    const int tid  = threadIdx.x;
    const int c    = blockIdx.y;
    const int base = blockIdx.x * GT;          // N % GT == 0: no tail

    if (tid < 128) {
        *(ushort4*)(sIdx + tid * 4) =
            *(const ushort4*)(nbr16 + (size_t)base * DEG + tid * 4);
    }
    __syncthreads();

    const unsigned char* slice = featF8 + (size_t)c * SLICE8;
    const int grp = tid >> 4;     // node slot 0..15
    const int ln  = tid & 15;     // dims 4*ln .. 4*ln+3 of the chunk
    const unsigned short* idxr = sIdx + grp * DEG;

    float s0 = 0.f, s1 = 0.f, s2 = 0.f, s3 = 0.f;
    #pragma unroll 8
    for (int j = 0; j < DEG; ++j) {
        int nb = idxr[j];
        unsigned v = *(const unsigned*)(slice + (size_t)nb * CDIM + ln * 4);
        f32x2 lo = __builtin_amdgcn_cvt_pk_f32_fp8(v, false);
        f32x2 hi = __builtin_amdgcn_cvt_pk_f32_fp8(v, true);
        s0 += lo[0]; s1 += lo[1]; s2 += hi[0]; s3 += hi[1];
    }
    const float sc = 1.0f / 32.0f;
    ushort4 o;
    o.x = f2bf(s0 * sc); o.y = f2bf(s1 * sc);
    o.z = f2bf(s2 * sc); o.w = f2bf(s3 * sc);
    const int node = base + grp;
    *(ushort4*)(meanb + (size_t)node * IN_DIM + c * CDIM + ln * 4) = o;
}

// ---------------- persistent GEMM: W1/W2 in registers, K-loop = LDS + MFMA only ----------------
// MFMA fragment layouts (measured, learn_hip m89/m91/m120):
//   A operand: lane holds A[m = lane&15][k = (lane>>4)*8 + j], j=0..7
//   B operand (W row-major [n][k]): lane holds W[n = lane&15][k = (lane>>4)*8 + j]
//   C/D: col(n) = lane&15, row(m) = (lane>>4)*4 + reg
__global__ __launch_bounds__(512, 2)
void sage_gemm_reg(const unsigned short* __restrict__ featb,  // [N,256] bf16
                   const unsigned short* __restrict__ meanb,  // [N,256] bf16
                   const unsigned short* __restrict__ W1b,    // [256,512] bf16
                   const float*          __restrict__ b1,
                   const unsigned short* __restrict__ W2b,    // [128,256] bf16
                   const float*          __restrict__ b2,
                   float*                __restrict__ out)    // [N,128]
{
    __shared__ __align__(16) unsigned short sC[MT * CSTR];  // 66560 B
    __shared__ __align__(16) unsigned short sH[MT * HSTR];  // 33792 B (100352 total, 1 blk/CU)

    const int tid  = threadIdx.x;
    const int lane = tid & 63;
    const int wave = tid >> 6;     // 0..7
    const int r    = lane & 15;
    const int q    = lane >> 4;

    // ---- one-time: load this wave's W fragments into registers ----
    bf16x8 w1f[2][16];   // 128 VGPR: h-cols wave*32 + nt*16 + r
    #pragma unroll
    for (int nt = 0; nt < 2; ++nt) {
        const size_t nrow = (size_t)(wave * 32 + nt * 16 + r) * K1;
        #pragma unroll
        for (int kk = 0; kk < 16; ++kk)
            w1f[nt][kk] = *(const bf16x8*)(W1b + nrow + kk * 32 + q * 8);
    }
    bf16x8 w2f[8];       // 32 VGPR: out-col wave*16 + r
    {
        const size_t orow = (size_t)(wave * 16 + r) * HID;
        #pragma unroll
        for (int kk = 0; kk < 8; ++kk)
            w2f[kk] = *(const bf16x8*)(W2b + orow + kk * 32 + q * 8);
    }
    const float bias1a = b1[wave * 32 + r];
    const float bias1b = b1[wave * 32 + 16 + r];
    const float bias2  = b2[wave * 16 + r];

    // ---- persistent tile loop ----
    for (int tile = blockIdx.x; tile < NTILES; tile += GBLK) {
        const int base = tile * MT;

        // Phase 1: stage combined = [self | mean] rows (16 B/lane)
        for (int i = wave * 8; i < wave * 8 + 8; ++i) {
            const int node = base + i;
            if (node < N_NODES) {
                const unsigned short* src = (lane < 32)
                    ? featb + (size_t)node * IN_DIM + lane * 8
                    : meanb + (size_t)node * IN_DIM + (lane - 32) * 8;
                *(bf16x8*)(&sC[i * CSTR + lane * 8]) = *(const bf16x8*)src;
            } else {
                bf16x8 z = (bf16x8){0, 0, 0, 0, 0, 0, 0, 0};
                *(bf16x8*)(&sC[i * CSTR + lane * 8]) = z;
            }
        }
        __syncthreads();   // (A) sC ready

        // Phase 2: h = relu(C @ W1^T + b1); wave covers h-cols [wave*32, wave*32+32)
        {
            f32x4 acc[4][2];
            #pragma unroll
            for (int mt = 0; mt < 4; ++mt)
                #pragma unroll
                for (int nt = 0; nt < 2; ++nt)
                    acc[mt][nt] = (f32x4){0.f, 0.f, 0.f, 0.f};

            #pragma unroll
            for (int kk = 0; kk < 16; ++kk) {
                bf16x8 a[4];
                #pragma unroll
                for (int mt = 0; mt < 4; ++mt)
                    a[mt] = *(const bf16x8*)(&sC[(mt * 16 + r) * CSTR + kk * 32 + q * 8]);
                #pragma unroll
                for (int nt = 0; nt < 2; ++nt)
                    #pragma unroll
                    for (int mt = 0; mt < 4; ++mt)
                        acc[mt][nt] = __builtin_amdgcn_mfma_f32_16x16x32_bf16(a[mt], w1f[nt][kk], acc[mt][nt], 0, 0, 0);
            }
            // write h to sH (separate buffer: no barrier needed before writes)
            #pragma unroll
            for (int nt = 0; nt < 2; ++nt) {
                const int n = wave * 32 + nt * 16 + r;
                const float bias = nt ? bias1b : bias1a;
                #pragma unroll
                for (int mt = 0; mt < 4; ++mt)
                    #pragma unroll
                    for (int g = 0; g < 4; ++g) {
                        const int m = mt * 16 + q * 4 + g;
                        float v = acc[mt][nt][g] + bias;
                        sH[m * HSTR + n] = f2bf(v > 0.f ? v : 0.f);
                    }
            }
        }
        __syncthreads();   // (B) sH ready (also: all waves done reading sC)

        // Phase 3: out = relu(h @ W2^T + b2); wave covers out-cols [wave*16, wave*16+16)
        {
            f32x4 acc3[4];
            #pragma unroll
            for (int mt = 0; mt < 4; ++mt) acc3[mt] = (f32x4){0.f, 0.f, 0.f, 0.f};

            #pragma unroll
            for (int kk = 0; kk < 8; ++kk)
                #pragma unroll
                for (int mt = 0; mt < 4; ++mt) {
                    bf16x8 a = *(const bf16x8*)(&sH[(mt * 16 + r) * HSTR + kk * 32 + q * 8]);
                    acc3[mt] = __builtin_amdgcn_mfma_f32_16x16x32_bf16(a, w2f[kk], acc3[mt], 0, 0, 0);
                }

            const int o = wave * 16 + r;
            #pragma unroll
            for (int mt = 0; mt < 4; ++mt)
                #pragma unroll
                for (int g = 0; g < 4; ++g) {
                    const int m = mt * 16 + q * 4 + g;
                    const int node = base + m;
                    if (node < N_NODES) {
                        float v = acc3[mt][g] + bias2;
                        out[(size_t)node * OUT_DIM + o] = v > 0.f ? v : 0.f;
                    }
                }
        }
        // next iteration's staging writes sC only; all sC readers passed barrier (B),
        // and its phase-2 sH writes sit behind next barrier (A) — no extra barrier needed.
    }
}

// ---------------- naive fp32 fallback (only if ws too small) ----------------
__global__ __launch_bounds__(256)
void sage_naive(const float* __restrict__ feat, const int* __restrict__ nbr,
                const float* __restrict__ W1, const float* __restrict__ b1,
                const float* __restrict__ W2, const float* __restrict__ b2,
                float* __restrict__ out) {
    __shared__ float comb[K1];
    __shared__ float h[HID];
    const int node = blockIdx.x;
    const int t = threadIdx.x;  // 256
    comb[t] = feat[(size_t)node * IN_DIM + t];
    float acc = 0.f;
    for (int d = 0; d < DEG; ++d) {
        int nb = clampN(nbr[node * DEG + d]);
        acc += feat[(size_t)nb * IN_DIM + t];
    }
    comb[IN_DIM + t] = acc * (1.0f / 32.0f);
    __syncthreads();
    float s = b1[t];
    for (int k = 0; k < K1; ++k) s += comb[k] * W1[(size_t)t * K1 + k];
    h[t] = s > 0.f ? s : 0.f;
    __syncthreads();
    if (t < OUT_DIM) {
        float s2 = b2[t];
        for (int k = 0; k < HID; ++k) s2 += h[k] * W2[(size_t)t * HID + k];
        out[(size_t)node * OUT_DIM + t] = s2 > 0.f ? s2 : 0.f;
    }
}

extern "C" void kernel_launch(void* const* d_in, const int* in_sizes, int n_in,
                              void* d_out, int out_size, void* d_ws, size_t ws_size,
                              hipStream_t stream) {
    const float* feat = (const float*)d_in[0];
    const int*   nbr  = (const int*)d_in[1];
    const float* W1   = (const float*)d_in[2];
    const float* b1   = (const float*)d_in[3];
    const float* W2   = (const float*)d_in[4];
    const float* b2   = (const float*)d_in[5];
    float* out = (float*)d_out;

    const size_t feat_elems = (size_t)N_NODES * IN_DIM;   // 12.8M
    const size_t w1_elems   = (size_t)HID * K1;
    const size_t w2_elems   = (size_t)OUT_DIM * HID;
    const size_t mean_elems = (size_t)N_NODES * IN_DIM;
    const size_t idx_elems  = (size_t)N_NODES * DEG;
    const size_t u16_elems  = feat_elems + w1_elems + w2_elems + mean_elems + idx_elems;
    const size_t need = u16_elems * sizeof(unsigned short)
                      + (size_t)NCHUNK * SLICE8;          // ~67.6 MB

    if (ws_size >= need) {
        unsigned short* featb  = (unsigned short*)d_ws;
        unsigned short* W1b    = featb + feat_elems;
        unsigned short* W2b    = W1b + w1_elems;
        unsigned short* meanb  = W2b + w2_elems;
        unsigned short* nbr16  = meanb + mean_elems;
        unsigned char*  featF8 = (unsigned char*)(nbr16 + idx_elems);

        prep_all<<<FEAT_BLKS + 256, 256, 0, stream>>>(feat, W1, W2, nbr,
                                                      featb, featF8, W1b, W2b, nbr16);
        gather_mean_fp8<<<dim3(N_NODES / GT, NCHUNK), 256, 0, stream>>>(featF8, nbr16, meanb);
        sage_gemm_reg<<<GBLK, 512, 0, stream>>>(featb, meanb, W1b, b1, W2b, b2, out);
    } else {
        sage_naive<<<N_NODES, 256, 0, stream>>>(feat, nbr, W1, b1, W2, b2, out);
    }
}

// Round 7
// 174.256 us; speedup vs baseline: 1.6561x; 1.0737x over previous
//
#include <hip/hip_runtime.h>
#include <stdint.h>

// Problem constants (from reference)
#define N_NODES 50000
#define DEG     32
#define IN_DIM  256
#define K1      512   // 2*IN_DIM
#define HID     256
#define OUT_DIM 128

// fp8 gather tiling
#define NCHUNK  4
#define CDIM    64                          // dims per chunk (64 B fp8 per node-chunk)
#define SLICE8  ((size_t)N_NODES * CDIM)    // bytes per chunk slice (3.2 MB)
#define GT      16                          // nodes per gather block

// GEMM tiling
#define MT     32                           // nodes per tile
#define NTILES ((N_NODES + MT - 1) / MT)    // 1563
#define GBLK   256                          // persistent blocks (1/CU)
#define CSTR   520    // combined LDS row stride, bf16 elems (1040 B; row data 1024 B + 16 B pad)
#define HSTR   264    // h LDS row stride, bf16 elems (528 B)

typedef __bf16 bf16x8 __attribute__((ext_vector_type(8)));
typedef float  f32x4  __attribute__((ext_vector_type(4)));
typedef float  f32x2  __attribute__((ext_vector_type(2)));

#define PIN(x) asm volatile("" : "+v"(x))

__device__ __forceinline__ unsigned short f2bf(float f) {
    union { float f; unsigned u; } v; v.f = f;
    unsigned r = v.u + 0x7fffu + ((v.u >> 16) & 1u);  // RNE (inputs finite)
    return (unsigned short)(r >> 16);
}
__device__ __forceinline__ int clampN(int v) {
    return v < 0 ? 0 : (v >= N_NODES ? N_NODES - 1 : v);
}
__device__ __forceinline__ void async_copy16(const void* g, void* l) {
    __builtin_amdgcn_global_load_lds(
        (const __attribute__((address_space(1))) void*)g,
        (__attribute__((address_space(3))) void*)l, 16, 0, 0);
}

// ---------------- merged prep: feat->bf16 + fp8 tiled; W1/W2->bf16; nbr->u16 ----------------
#define FEAT_BLKS ((N_NODES + 7) / 8)   // 6250
__global__ __launch_bounds__(256)
void prep_all(const float* __restrict__ feat,
              const float* __restrict__ W1, const float* __restrict__ W2,
              const int*   __restrict__ nbr,
              unsigned short* __restrict__ featb,   // [N,256] bf16
              unsigned char*  __restrict__ featF8,  // [4][N][64] fp8 e4m3
              unsigned short* __restrict__ W1b, unsigned short* __restrict__ W2b,
              unsigned short* __restrict__ nbr16)
{
    const int t = threadIdx.x;
    if (blockIdx.x < FEAT_BLKS) {
        const int node = blockIdx.x * 8 + (t >> 5);  // 8 nodes/block
        const int seg  = t & 31;                     // dims seg*8 .. seg*8+7
        if (node < N_NODES) {
            const float4* src = (const float4*)(feat + (size_t)node * IN_DIM + seg * 8);
            float4 f0 = src[0], f1 = src[1];
            ushort4 o0, o1;
            o0.x = f2bf(f0.x); o0.y = f2bf(f0.y); o0.z = f2bf(f0.z); o0.w = f2bf(f0.w);
            o1.x = f2bf(f1.x); o1.y = f2bf(f1.y); o1.z = f2bf(f1.z); o1.w = f2bf(f1.w);
            unsigned short* db = featb + (size_t)node * IN_DIM + seg * 8;
            *(ushort4*)db       = o0;
            *(ushort4*)(db + 4) = o1;
            int u0 = 0, u1 = 0;
            u0 = __builtin_amdgcn_cvt_pk_fp8_f32(f0.x, f0.y, u0, false);
            u0 = __builtin_amdgcn_cvt_pk_fp8_f32(f0.z, f0.w, u0, true);
            u1 = __builtin_amdgcn_cvt_pk_fp8_f32(f1.x, f1.y, u1, false);
            u1 = __builtin_amdgcn_cvt_pk_fp8_f32(f1.z, f1.w, u1, true);
            const int c   = seg >> 3;
            const int off = (seg & 7) * 8;
            unsigned char* d8 = featF8 + (size_t)c * SLICE8 + (size_t)node * CDIM + off;
            ((int*)d8)[0] = u0;
            ((int*)d8)[1] = u1;
        }
    } else {
        const int bid = blockIdx.x - FEAT_BLKS;           // 0..255
        const int stride = 256 * 256 * 4;
        const int tid4 = (bid * 256 + t) * 4;
        for (int i = tid4; i < HID * K1; i += stride) {
            float4 f = *(const float4*)(W1 + i);
            ushort4 o; o.x = f2bf(f.x); o.y = f2bf(f.y); o.z = f2bf(f.z); o.w = f2bf(f.w);
            *(ushort4*)(W1b + i) = o;
        }
        for (int i = tid4; i < OUT_DIM * HID; i += stride) {
            float4 f = *(const float4*)(W2 + i);
            ushort4 o; o.x = f2bf(f.x); o.y = f2bf(f.y); o.z = f2bf(f.z); o.w = f2bf(f.w);
            *(ushort4*)(W2b + i) = o;
        }
        for (int i = tid4; i < N_NODES * DEG; i += stride) {
            int4 v = *(const int4*)(nbr + i);
            ushort4 o;
            o.x = (unsigned short)clampN(v.x); o.y = (unsigned short)clampN(v.y);
            o.z = (unsigned short)clampN(v.z); o.w = (unsigned short)clampN(v.w);
            *(ushort4*)(nbr16 + i) = o;
        }
    }
}

// ---------------- gather + mean: fp8 slices, full-unroll MLP ----------------
__global__ __launch_bounds__(256)
void gather_mean_fp8(const unsigned char*  __restrict__ featF8,
                     const unsigned short* __restrict__ nbr16,
                     unsigned short*       __restrict__ meanb)  // [N,256] bf16
{
    __shared__ unsigned short sIdx[GT * DEG];  // 1 KB
    const int tid  = threadIdx.x;
    const int c    = blockIdx.y;
    const int base = blockIdx.x * GT;          // N % GT == 0: no tail

    if (tid < 128) {
        *(ushort4*)(sIdx + tid * 4) =
            *(const ushort4*)(nbr16 + (size_t)base * DEG + tid * 4);
    }
    __syncthreads();

    const unsigned char* slice = featF8 + (size_t)c * SLICE8;
    const int grp = tid >> 4;     // node slot 0..15
    const int ln  = tid & 15;     // dims 4*ln .. 4*ln+3 of the chunk
    const unsigned short* idxr = sIdx + grp * DEG;

    // all 32 loads issued before any use: max memory-level parallelism
    unsigned vv[DEG];
    #pragma unroll
    for (int j = 0; j < DEG; ++j) {
        int nb = idxr[j];
        vv[j] = *(const unsigned*)(slice + (size_t)nb * CDIM + ln * 4);
    }
    float s0 = 0.f, s1 = 0.f, s2 = 0.f, s3 = 0.f;
    #pragma unroll
    for (int j = 0; j < DEG; ++j) {
        f32x2 lo = __builtin_amdgcn_cvt_pk_f32_fp8(vv[j], false);
        f32x2 hi = __builtin_amdgcn_cvt_pk_f32_fp8(vv[j], true);
        s0 += lo[0]; s1 += lo[1]; s2 += hi[0]; s3 += hi[1];
    }
    const float sc = 1.0f / 32.0f;
    ushort4 o;
    o.x = f2bf(s0 * sc); o.y = f2bf(s1 * sc);
    o.z = f2bf(s2 * sc); o.w = f2bf(s3 * sc);
    const int node = base + grp;
    *(ushort4*)(meanb + (size_t)node * IN_DIM + c * CDIM + ln * 4) = o;
}

// ---------------- persistent GEMM: dbuf async staging + pinned W fragments ----------------
// MFMA fragment layouts (measured, learn_hip m89/m91/m120):
//   A operand: lane holds A[m = lane&15][k = (lane>>4)*8 + j], j=0..7
//   B operand (W row-major [n][k]): lane holds W[n = lane&15][k = (lane>>4)*8 + j]
//   C/D: col(n) = lane&15, row(m) = (lane>>4)*4 + reg
__global__ __launch_bounds__(512, 2)
void sage_gemm_dbuf(const unsigned short* __restrict__ featb,  // [N,256] bf16
                    const unsigned short* __restrict__ meanb,  // [N,256] bf16
                    const unsigned short* __restrict__ W1b,    // [256,512] bf16
                    const float*          __restrict__ b1,
                    const unsigned short* __restrict__ W2b,    // [128,256] bf16
                    const float*          __restrict__ b2,
                    float*                __restrict__ out)    // [N,128]
{
    __shared__ __align__(16) unsigned short sC[2][MT * CSTR];  // 2 x 33280 B
    __shared__ __align__(16) unsigned short sH[MT * HSTR];     // 16896 B (83456 total)

    const int tid  = threadIdx.x;
    const int lane = tid & 63;
    const int wave = tid >> 6;     // 0..7
    const int r    = lane & 15;
    const int q    = lane >> 4;

    // ---- one-time: W fragments into registers, pinned against remat ----
    bf16x8 w1f[2][16];   // h-cols wave*32 + nt*16 + r
    #pragma unroll
    for (int nt = 0; nt < 2; ++nt) {
        const size_t nrow = (size_t)(wave * 32 + nt * 16 + r) * K1;
        #pragma unroll
        for (int kk = 0; kk < 16; ++kk) {
            w1f[nt][kk] = *(const bf16x8*)(W1b + nrow + kk * 32 + q * 8);
            PIN(w1f[nt][kk]);
        }
    }
    bf16x8 w2f[8];       // out-col wave*16 + r
    {
        const size_t orow = (size_t)(wave * 16 + r) * HID;
        #pragma unroll
        for (int kk = 0; kk < 8; ++kk) {
            w2f[kk] = *(const bf16x8*)(W2b + orow + kk * 32 + q * 8);
            PIN(w2f[kk]);
        }
    }
    const float bias1a = b1[wave * 32 + r];
    const float bias1b = b1[wave * 32 + 16 + r];
    const float bias2  = b2[wave * 16 + r];

    // per-lane source offset within a combined row (self 512B | mean 512B)
    // HW writes lane i at lds_base + i*16 -> exactly our row layout.
    auto stage = [&](int tile, int buf) {
        const int base = tile * MT;
        #pragma unroll
        for (int j = 0; j < 4; ++j) {
            const int i = wave * 4 + j;           // row 0..31 (wave-uniform)
            int node = base + i;
            if (node >= N_NODES) node = N_NODES - 1;
            const unsigned short* g = (lane < 32)
                ? featb + (size_t)node * IN_DIM + lane * 8
                : meanb + (size_t)node * IN_DIM + (lane - 32) * 8;
            async_copy16(g, &sC[buf][i * CSTR]);
        }
    };

    int tile = blockIdx.x;
    if (tile < NTILES) stage(tile, 0);
    int buf = 0;

    for (; tile < NTILES; tile += GBLK) {
        __syncthreads();   // compiler drains vmcnt before s_barrier: sC[buf] ready

        const int nxt = tile + GBLK;
        if (nxt < NTILES) stage(nxt, buf ^ 1);   // overlaps phase 2

        // ---- Phase 2: h = relu(C @ W1^T + b1); wave covers h-cols [wave*32, +32) ----
        {
            f32x4 acc[2][2];
            #pragma unroll
            for (int mt = 0; mt < 2; ++mt)
                #pragma unroll
                for (int nt = 0; nt < 2; ++nt)
                    acc[mt][nt] = (f32x4){0.f, 0.f, 0.f, 0.f};

            #pragma unroll
            for (int kk = 0; kk < 16; ++kk) {
                bf16x8 a0 = *(const bf16x8*)(&sC[buf][r * CSTR + kk * 32 + q * 8]);
                bf16x8 a1 = *(const bf16x8*)(&sC[buf][(16 + r) * CSTR + kk * 32 + q * 8]);
                acc[0][0] = __builtin_amdgcn_mfma_f32_16x16x32_bf16(a0, w1f[0][kk], acc[0][0], 0, 0, 0);
                acc[1][0] = __builtin_amdgcn_mfma_f32_16x16x32_bf16(a1, w1f[0][kk], acc[1][0], 0, 0, 0);
                acc[0][1] = __builtin_amdgcn_mfma_f32_16x16x32_bf16(a0, w1f[1][kk], acc[0][1], 0, 0, 0);
                acc[1][1] = __builtin_amdgcn_mfma_f32_16x16x32_bf16(a1, w1f[1][kk], acc[1][1], 0, 0, 0);
            }
            #pragma unroll
            for (int nt = 0; nt < 2; ++nt) {
                const int n = wave * 32 + nt * 16 + r;
                const float bias = nt ? bias1b : bias1a;
                #pragma unroll
                for (int mt = 0; mt < 2; ++mt)
                    #pragma unroll
                    for (int g = 0; g < 4; ++g) {
                        const int m = mt * 16 + q * 4 + g;
                        float v = acc[mt][nt][g] + bias;
                        sH[m * HSTR + n] = f2bf(v > 0.f ? v : 0.f);
                    }
            }
        }
        __syncthreads();   // sH ready (also drains the prefetch early — accepted)

        // ---- Phase 3: out = relu(h @ W2^T + b2); wave covers out-cols [wave*16, +16) ----
        {
            f32x4 acc3[2];
            acc3[0] = (f32x4){0.f, 0.f, 0.f, 0.f};
            acc3[1] = (f32x4){0.f, 0.f, 0.f, 0.f};
            #pragma unroll
            for (int kk = 0; kk < 8; ++kk) {
                bf16x8 h0 = *(const bf16x8*)(&sH[r * HSTR + kk * 32 + q * 8]);
                bf16x8 h1 = *(const bf16x8*)(&sH[(16 + r) * HSTR + kk * 32 + q * 8]);
                acc3[0] = __builtin_amdgcn_mfma_f32_16x16x32_bf16(h0, w2f[kk], acc3[0], 0, 0, 0);
                acc3[1] = __builtin_amdgcn_mfma_f32_16x16x32_bf16(h1, w2f[kk], acc3[1], 0, 0, 0);
            }
            const int base = tile * MT;
            const int o = wave * 16 + r;
            #pragma unroll
            for (int mt = 0; mt < 2; ++mt)
                #pragma unroll
                for (int g = 0; g < 4; ++g) {
                    const int m = mt * 16 + q * 4 + g;
                    const int node = base + m;
                    if (node < N_NODES) {
                        float v = acc3[mt][g] + bias2;
                        out[(size_t)node * OUT_DIM + o] = v > 0.f ? v : 0.f;
                    }
                }
        }
        buf ^= 1;
    }
}

// ---------------- naive fp32 fallback (only if ws too small) ----------------
__global__ __launch_bounds__(256)
void sage_naive(const float* __restrict__ feat, const int* __restrict__ nbr,
                const float* __restrict__ W1, const float* __restrict__ b1,
                const float* __restrict__ W2, const float* __restrict__ b2,
                float* __restrict__ out) {
    __shared__ float comb[K1];
    __shared__ float h[HID];
    const int node = blockIdx.x;
    const int t = threadIdx.x;  // 256
    comb[t] = feat[(size_t)node * IN_DIM + t];
    float acc = 0.f;
    for (int d = 0; d < DEG; ++d) {
        int nb = clampN(nbr[node * DEG + d]);
        acc += feat[(size_t)nb * IN_DIM + t];
    }
    comb[IN_DIM + t] = acc * (1.0f / 32.0f);
    __syncthreads();
    float s = b1[t];
    for (int k = 0; k < K1; ++k) s += comb[k] * W1[(size_t)t * K1 + k];
    h[t] = s > 0.f ? s : 0.f;
    __syncthreads();
    if (t < OUT_DIM) {
        float s2 = b2[t];
        for (int k = 0; k < HID; ++k) s2 += h[k] * W2[(size_t)t * HID + k];
        out[(size_t)node * OUT_DIM + t] = s2 > 0.f ? s2 : 0.f;
    }
}

extern "C" void kernel_launch(void* const* d_in, const int* in_sizes, int n_in,
                              void* d_out, int out_size, void* d_ws, size_t ws_size,
                              hipStream_t stream) {
    const float* feat = (const float*)d_in[0];
    const int*   nbr  = (const int*)d_in[1];
    const float* W1   = (const float*)d_in[2];
    const float* b1   = (const float*)d_in[3];
    const float* W2   = (const float*)d_in[4];
    const float* b2   = (const float*)d_in[5];
    float* out = (float*)d_out;

    const size_t feat_elems = (size_t)N_NODES * IN_DIM;   // 12.8M
    const size_t w1_elems   = (size_t)HID * K1;
    const size_t w2_elems   = (size_t)OUT_DIM * HID;
    const size_t mean_elems = (size_t)N_NODES * IN_DIM;
    const size_t idx_elems  = (size_t)N_NODES * DEG;
    const size_t u16_elems  = feat_elems + w1_elems + w2_elems + mean_elems + idx_elems;
    const size_t need = u16_elems * sizeof(unsigned short)
                      + (size_t)NCHUNK * SLICE8;          // ~67.6 MB

    if (ws_size >= need) {
        unsigned short* featb  = (unsigned short*)d_ws;
        unsigned short* W1b    = featb + feat_elems;
        unsigned short* W2b    = W1b + w1_elems;
        unsigned short* meanb  = W2b + w2_elems;
        unsigned short* nbr16  = meanb + mean_elems;
        unsigned char*  featF8 = (unsigned char*)(nbr16 + idx_elems);

        prep_all<<<FEAT_BLKS + 256, 256, 0, stream>>>(feat, W1, W2, nbr,
                                                      featb, featF8, W1b, W2b, nbr16);
        gather_mean_fp8<<<dim3(N_NODES / GT, NCHUNK), 256, 0, stream>>>(featF8, nbr16, meanb);
        sage_gemm_dbuf<<<GBLK, 512, 0, stream>>>(featb, meanb, W1b, b1, W2b, b2, out);
    } else {
        sage_naive<<<N_NODES, 256, 0, stream>>>(feat, nbr, W1, b1, W2, b2, out);
    }
}